// Round 6
// baseline (589.670 us; speedup 1.0000x reference)
//
#include <hip/hip_runtime.h>

#define BB 256
#define TT 512
#define NN 128
#define GO_IDX 1
#define EOS_IDX 2
#define TSPLIT 496            // bp rows t in [1,TSPLIT) in LDS; [TSPLIT,512) in d_ws (proven 524KB)
#define NEGV (-10000.0f)
// padded alpha slot: x + (x>>4)*4 -> 8 groups of 16 at 20-float stride (banks 0,20,8,28,16,4,24,12)
#define ASLOT(x) ((x) + (((x) >> 4) << 2))

// ---------- pre-pass: in-place row-wise log_softmax ----------
// one row per 32-lane half-wave, float4; per-row perturbation vs np order is
// ~1 ulp of ls, absorbed below alpha's ulp (see R5 post-mortem) -> decisions safe
__global__ __launch_bounds__(256) void lsm_kernel(float* __restrict__ u) {
    const int g0 = (blockIdx.x * 256 + threadIdx.x) >> 5;   // half-wave id, 0..16383
    const int l  = threadIdx.x & 31;
    const int NG = 2048 * 8;                                // groups per pass
    float4* base = (float4*)u;                              // row r: base[r*32 + l]
    int row = g0;
    float4 v = base[(size_t)row * 32 + l];
#pragma unroll
    for (int it = 0; it < 8; ++it) {                        // 8*16384 = 131072 rows
        const int nrow = row + NG;
        float4 vn = make_float4(0.f, 0.f, 0.f, 0.f);
        if (it < 7) vn = base[(size_t)nrow * 32 + l];       // prefetch next row
        float m = fmaxf(fmaxf(v.x, v.y), fmaxf(v.z, v.w));
#pragma unroll
        for (int off = 16; off; off >>= 1) m = fmaxf(m, __shfl_xor(m, off, 64));
        float s = expf(v.x - m) + expf(v.y - m) + expf(v.z - m) + expf(v.w - m);
#pragma unroll
        for (int off = 16; off; off >>= 1) s += __shfl_xor(s, off, 64);
        float ls = logf(s);
        base[(size_t)row * 32 + l] =
            make_float4((v.x - m) - ls, (v.y - m) - ls, (v.z - m) - ls, (v.w - m) - ls);
        v = vn; row = nrow;
    }
}

// ---------- serial Viterbi: 1024 threads, 8 threads per cur (4 waves/SIMD) ----------
__global__ __launch_bounds__(1024) void viterbi_kernel(
    const float* __restrict__ probs,     // [B,T,N] log-softmaxed
    const float* __restrict__ trans,     // [1,N,N] trans0[cur][prev]
    const int*   __restrict__ lengths_raw,
    float* __restrict__ out,             // [B*T] preds then [B] scores
    unsigned char* __restrict__ ws)
{
    __shared__ unsigned char bps[(TSPLIT - 1) * NN];   // 63360 B
    __shared__ __align__(16) float alpha[2][160];      // padded, double-buffered
    __shared__ float fin_v[2];
    __shared__ int   fin_i[2];

    const int tid  = threadIdx.x;
    const int b    = blockIdx.x;
    const int wave = tid >> 6;
    const int lane = tid & 63;
    const int q    = tid & 7;              // prev-eighth owned by this lane
    const int cur  = tid >> 3;             // tag owned by this octet (0..127)

    int len;
    {
        int probe = lengths_raw[1];        // ==0 iff int64 (lengths >= 256 > 0)
        len = (probe == 0) ? lengths_raw[2 * b] : lengths_raw[b];
    }

    // trans chunk in registers: trans0[cur][q*16 + j], j in [0,16)
    float tr[16];
    {
        const float4* t4 = (const float4*)(trans + cur * NN + q * 16);
#pragma unroll
        for (int i = 0; i < 4; ++i) {
            float4 v = t4[i];
            tr[4*i+0] = v.x; tr[4*i+1] = v.y; tr[4*i+2] = v.z; tr[4*i+3] = v.w;
        }
    }

    if (tid < NN) alpha[0][ASLOT(tid)] = (tid == GO_IDX) ? 0.0f : NEGV;

    const float* pb = probs + (size_t)b * TT * NN;
    unsigned char* wst = ws + (size_t)b * ((TT - TSPLIT) * NN);

    // 8-deep register window of p[t][cur] (q==0 lanes only)
    float P[8], Nx[8];
    if (q == 0) {
#pragma unroll
        for (int k = 0; k < 8; ++k) P[k] = pb[k * NN + cur];
    }
    __syncthreads();

    const int nG = (len + 7) >> 3;
    for (int g = 0; g < nG; ++g) {
        const int tb = g * 8;
        if (q == 0) {
#pragma unroll
            for (int k = 0; k < 8; ++k) {
                int tt = tb + 8 + k; if (tt > TT - 1) tt = TT - 1;
                Nx[k] = pb[tt * NN + cur];
            }
        }
#pragma unroll
        for (int k = 0; k < 8; ++k) {
            const int t = tb + k;
            if (t < len) {                         // uniform per block
                const float* ra = alpha[t & 1];
                float*       wa = alpha[(t & 1) ^ 1];
                const float4* a4 = (const float4*)(ra + q * 20);  // conflict-free bases
                float bv[4]; int bi[4];
#pragma unroll
                for (int c = 0; c < 4; ++c) {      // 4 chains x 4 prevs
                    float4 a = a4[c];
                    const int base = c * 4;
                    bv[c] = a.x + tr[base + 0]; bi[c] = base + 0;
                    float x1 = a.y + tr[base + 1]; if (x1 > bv[c]) { bv[c] = x1; bi[c] = base + 1; }
                    float x2 = a.z + tr[base + 2]; if (x2 > bv[c]) { bv[c] = x2; bi[c] = base + 2; }
                    float x3 = a.w + tr[base + 3]; if (x3 > bv[c]) { bv[c] = x3; bi[c] = base + 3; }
                }
                float best = bv[0]; int bp = bi[0];
#pragma unroll
                for (int c = 1; c < 4; ++c) { if (bv[c] > best) { best = bv[c]; bp = bi[c]; } }
                bp += q * 16;                      // absolute prev index

                // 3-level octet combine, values only; exactly one winner lane writes bp.
                // first-max tie-break: lower q (= lower prev range) wins every tie.
                float v1 = __shfl_xor(best, 1, 64);
                bool  w1 = (q & 1) ? (best > v1) : (best >= v1);
                float m1 = fmaxf(best, v1);
                float v2 = __shfl_xor(m1, 2, 64);
                bool  w2 = (q & 2) ? (m1 > v2) : (m1 >= v2);
                float m2 = fmaxf(m1, v2);
                float v4 = __shfl_xor(m2, 4, 64);
                bool  w3 = (q & 4) ? (m2 > v4) : (m2 >= v4);
                float M  = fmaxf(m2, v4);
                if (t >= 1 && (w1 && w2 && w3)) {
                    if (t < TSPLIT) bps[(t - 1) * NN + cur] = (unsigned char)bp;
                    else            wst[(t - TSPLIT) * NN + cur] = (unsigned char)bp;
                }
                if (q == 0) wa[ASLOT(cur)] = M + P[k];
                __syncthreads();
            }
        }
#pragma unroll
        for (int k = 0; k < 8; ++k) P[k] = Nx[k];
    }

    __threadfence();   // tail bp global writes visible to thread 0

    // terminal: argmax(alpha + trans0[EOS][:]), first-max tie-break
    if (tid < NN) {
        float v = alpha[len & 1][ASLOT(tid)] + trans[EOS_IDX * NN + tid];
        int idx = tid;
#pragma unroll
        for (int off = 32; off; off >>= 1) {
            float ov = __shfl_xor(v, off, 64);
            int   oi = __shfl_xor(idx, off, 64);
            if (ov > v || (ov == v && oi < idx)) { v = ov; idx = oi; }
        }
        if (lane == 0) { fin_v[wave] = v; fin_i[wave] = idx; }
    }

    for (int t = len + tid; t < TT; t += 1024) out[(size_t)b * TT + t] = 0.0f;
    __syncthreads();

    if (tid == 0) {
        float v0 = fin_v[0], v1 = fin_v[1];
        int   i0 = fin_i[0], i1 = fin_i[1];
        float sc; int tag;
        if (v1 > v0) { sc = v1; tag = i1; }
        else         { sc = v0; tag = i0; }
        out[(size_t)BB * TT + b] = sc;

        for (int t = len - 1; t >= 0; --t) {
            out[(size_t)b * TT + t] = (float)tag;
            if (t >= 1) {
                int nb;
                if (t < TSPLIT) nb = bps[(t - 1) * NN + tag];
                else            nb = ((volatile const unsigned char*)wst)[(t - TSPLIT) * NN + tag];
                tag = nb;
            }
        }
    }
}

extern "C" void kernel_launch(void* const* d_in, const int* in_sizes, int n_in,
                              void* d_out, int out_size, void* d_ws, size_t ws_size,
                              hipStream_t stream) {
    float*       unaries = (float*)d_in[0];          // transformed in-place to log-softmax
    const float* trans   = (const float*)d_in[1];
    const int*   lengths = (const int*)d_in[2];
    float* out = (float*)d_out;
    unsigned char* ws = (unsigned char*)d_ws;

    hipLaunchKernelGGL(lsm_kernel, dim3(2048), dim3(256), 0, stream, unaries);
    hipLaunchKernelGGL(viterbi_kernel, dim3(BB), dim3(1024), 0, stream,
                       unaries, trans, lengths, out, ws);
}